// Round 10
// baseline (1729.571 us; speedup 1.0000x reference)
//
#include <hip/hip_runtime.h>
#include <cstdint>
#include <cstddef>
#include <cmath>

#define H  2048
#define BB 2048   // batch
#define TT 64     // time steps
#define NC 10     // classes

typedef __bf16 bf16;
typedef bf16  bf16x8 __attribute__((ext_vector_type(8)));
typedef float f32x4  __attribute__((ext_vector_type(4)));

// ---------------------------------------------------------------------------
// async global->LDS, 16B per lane. LDS dest is wave-uniform base + lane*16;
// global source is per-lane.
// ---------------------------------------------------------------------------
__device__ __forceinline__ void load_lds16(const void* g, void* l) {
    __builtin_amdgcn_global_load_lds(
        (__attribute__((address_space(1))) void*)(void*)g,
        (__attribute__((address_space(3))) void*)l,
        16, 0, 0);
}

// ---------------------------------------------------------------------------
// FRAG-MAJOR layout (W_hh and S, since R12).
// For a matrix [R rows][H k-cols] (bf16):
//   subtile (r16, k32) = 16 rows x 32 k = 1024 B at id = r16*(H/32) + k32.
//   lane-slot l (16 B) holds M[r16*16 + (l&15)][k32*32 + (l>>4)*8 .. +8]
// = exactly the v_mfma_f32_16x16x32_bf16 A/B fragment, so a wave's frag load
// is ONE coalesced 1 KB segment: base + id*512 + lane*8 (bf16 elems).
// ---------------------------------------------------------------------------
__global__ void w_shuffle_kernel(const float* __restrict__ Whh,
                                 bf16* __restrict__ Wshuf) {
    int tid = blockIdx.x * blockDim.x + threadIdx.x;   // 0 .. H*H/8-1
    int sub = tid >> 6;          // subtile id
    int l   = tid & 63;          // dest lane slot
    int n16 = sub >> 6;          // 0..127
    int k32 = sub & 63;          // 0..63
    int n = n16 * 16 + (l & 15);
    int k = k32 * 32 + (l >> 4) * 8;
    const float* src = Whh + (size_t)n * H + k;
    bf16x8 o;
#pragma unroll
    for (int j = 0; j < 8; ++j) o[j] = (bf16)src[j];
    *(bf16x8*)(Wshuf + (size_t)tid * 8) = o;
}

// ---------------------------------------------------------------------------
// t = 0: S[b,i] = tanh(Whx[i]*x[b,0] + bh[i]), written FRAG-MAJOR.
// ---------------------------------------------------------------------------
__global__ void rnn_init(const float* __restrict__ x,     // [B, T]
                         const float* __restrict__ Whx,   // [H]
                         const float* __restrict__ bh,    // [H]
                         bf16* __restrict__ S) {          // frag-major
    int b  = blockIdx.x;
    int i0 = threadIdx.x * 8;
    float xv = x[(size_t)b * TT];
    bf16x8 o;
#pragma unroll
    for (int j = 0; j < 8; ++j)
        o[j] = (bf16)tanhf(Whx[i0 + j] * xv + bh[i0 + j]);
    size_t sub  = (size_t)(b >> 4) * 64 + (i0 >> 5);
    size_t slot = (size_t)(b & 15) | (size_t)(((i0 >> 3) & 3) << 4);
    *(bf16x8*)(S + (sub * 64 + slot) * 8) = o;
}

// ---------------------------------------------------------------------------
// One RNN time step, Round-20 "B on the VMEM pipe, A on the LDS pipe":
//   Sw[b,i] = tanh( sum_k Sr[b,k]*W[i,k] + Whx[i]*x[b,t] + bh[i] )
//
// R19 post-mortem: per-instruction LDS model (12 cy/ds_read_b128, m134)
// shows the LDS pipe at ~1100 cy/phase (64 reads + 32 stage-writes) vs
// MFMA 620 / VMEM 571 — the LDS instruction traffic is the wall and the
// schedule is already ~85% overlapped. Fix: route B fragments over the
// VMEM pipe (reg-direct 1 KB coalesced loads from the XCD-L2-RESIDENT W
// panel; 2x dup, twin reads may L1-hit). A stays on the gload_lds + LDS
// path. New per-phase budget: LDS 544 cy, VMEM 857 cy, MFMA 620 cy.
//
//   - Unlike R12/R14's failed reg-direct: B is L2-resident (XCD-owns-n),
//     loads are single-segment coalesced, and the R19 read-ahead pipeline
//     hides their latency (B banks ping-pong; compiler emits the precise
//     counted vmcnt for the reg deps).
//   - A ring shrinks to 4 x 16 KB (16 segs: [0..7] lo-chunk m16, [8..15]
//     hi-chunk m16). Manual counted vmcnt guards ONLY A stages:
//     per phase issue = 2 gload_lds + 4 B-loads = 6 vmcnt ops. Ast(p+1)
//     was the FIRST 2 ops of phase p-2 -> 4 (rest of p-2) + 6 (p-1) = 10
//     newer ops => steady wait vmcnt(10); phase 0 = 6; tail 10/8/0.
//   - Slot overwrite safety: ISSUE_A(p+3) targets slot (p-1)&3, whose
//     ds_reads finished in phase p-2, two barriers ago.
//   - Split-K geometry/reduction/epilogue identical to R19 (8 waves,
//     64x64 quadrants, pair reduction) -> absmax unchanged (2.44e-4).
//     Reduction/transpose reuse the 64 KB ring; one extra __syncthreads
//     separates reduction reads from transpose writes (regions overlap).
// ---------------------------------------------------------------------------
#define PH_WAIT(NSTR) asm volatile("s_waitcnt vmcnt(" NSTR ")" ::: "memory")
#define SBAR0()       __builtin_amdgcn_sched_barrier(0)

__launch_bounds__(512)
__global__ void rnn_step(const float* __restrict__ x,     // [B, T]
                         const float* __restrict__ Whx,   // [H]
                         const float* __restrict__ bh,    // [H]
                         const bf16*  __restrict__ Wshuf, // frag-major W_hh
                         const bf16*  __restrict__ Sr,    // frag-major S read
                         bf16* __restrict__ Sw,           // frag-major S write
                         int t) {
    // A ring slot = 16 segs x 1 KB: segs 0..7 = chunk-lo m16 0..7,
    //                               segs 8..15 = chunk-hi m16 0..7.
    __shared__ __align__(16) char Ls[4][16384];   // 64 KB

    const int tid  = threadIdx.x;
    const int w    = tid >> 6;          // wave 0..7
    const int lane = tid & 63;
    const int lrow = lane & 15;
    const int quad = lane >> 4;

    // XCD-owns-n mapping: XCD x covers n-cols [x*256, x*256+256).
    const int xcd = blockIdx.x & 7;
    const int loc = blockIdx.x >> 3;               // 0..31
    const int bm0 = (loc >> 1) * 128;              // batch-row tile origin
    const int bn0 = xcd * 256 + (loc & 1) * 128;   // hidden-col tile origin

    const int kh   = w >> 2;                       // K-half (0: k<1024)
    const int s    = w & 3;                        // quadrant id
    const int qm   = s & 1;                        // m-quadrant (64 rows)
    const int qn   = s >> 1;                       // n-quadrant (64 cols)
    const int cn0  = bn0 + qn * 64;                // wave's first col

    // A staging source: wave w owns A m16 subtile (bm0>>4)+w, both k-halves.
    const char* srcA = (const char*)Sr +
        ((size_t)((bm0 >> 4) + w) * 64) * 1024 + (size_t)lane * 16;
    // B reg-load base: block's n16 panel start, per-lane +lane*16B.
    const char* srcB = (const char*)Wshuf +
        ((size_t)(bn0 >> 4) * 64) * 1024 + (size_t)lane * 16;

    f32x4 acc[4][4];
#pragma unroll
    for (int i = 0; i < 4; ++i)
#pragma unroll
        for (int j = 0; j < 4; ++j) acc[i][j] = (f32x4){0.f, 0.f, 0.f, 0.f};

    // fragment ping-pong banks (static names; rule #20)
    bf16x8 Ae[4], Be[4], Ao[4], Bo[4];

    // ---- A-stage for phase pp into ring slot RI (2 VMEM ops) ----
#define ISSUE_A(RI, pp)                                                      \
    {                                                                        \
        load_lds16(srcA + (size_t)(pp) * 1024,        &Ls[RI][w * 1024]);    \
        load_lds16(srcA + (size_t)(32 + (pp)) * 1024, &Ls[RI][(8 + w) * 1024]); \
    }

    // ---- B reg-loads for phase pp into bank Bx (4 VMEM ops, 1 KB each) ----
#define BLOAD(Bx, pp)                                                        \
    {                                                                        \
        _Pragma("unroll")                                                    \
        for (int fn = 0; fn < 4; ++fn)                                       \
            Bx[fn] = *(const bf16x8*)(srcB +                                 \
                ((size_t)(qn * 4 + fn) * 64 + 32 * kh + (pp)) * 1024);       \
    }

    // ---- A fragment ds_reads of ring slot RI into bank Ax (4 ops) ----
#define DSREAD_A(Ax, RI)                                                     \
    {                                                                        \
        _Pragma("unroll")                                                    \
        for (int fm = 0; fm < 4; ++fm)                                       \
            Ax[fm] = *(const bf16x8*)&Ls[RI]                                 \
                [(kh * 8 + qm * 4 + fm) * 1024 + lane * 16];                 \
    }

    // ---- 16 MFMAs on bank (Ax, Bx) ----
#define MFMAS(Ax, Bx)                                                        \
    {                                                                        \
        __builtin_amdgcn_s_setprio(1);                                       \
        _Pragma("unroll")                                                    \
        for (int fm = 0; fm < 4; ++fm)                                       \
            _Pragma("unroll")                                                \
            for (int fn = 0; fn < 4; ++fn)                                   \
                acc[fm][fn] = __builtin_amdgcn_mfma_f32_16x16x32_bf16(       \
                    Ax[fm], Bx[fn], acc[fm][fn], 0, 0, 0);                   \
        __builtin_amdgcn_s_setprio(0);                                       \
    }

    // phase p: wait W (A-stage p+1 resident), barrier, issue A-stage p+3,
    // load B(p+1) regs + ds_read A(p+1) slot, MFMA on current banks.
#define PHASE(RNext, RIss, p, W, DOISS, DOREAD, AN, BN, AC, BC)              \
    {                                                                        \
        PH_WAIT(W);                                                          \
        SBAR0();                                                             \
        __builtin_amdgcn_s_barrier();                                        \
        SBAR0();                                                             \
        if (DOISS) ISSUE_A(RIss, (p) + 3);                                   \
        if (DOREAD) { BLOAD(BN, (p) + 1); DSREAD_A(AN, RNext); }             \
        MFMAS(AC, BC);                                                       \
    }

    // prologue: A-stages 0,1,2 (ops 1-6); B(0) (ops 7-10); wait A(0)
    // (8 newer ops in flight); barrier; pre-read slot 0.
    ISSUE_A(0, 0); SBAR0();
    ISSUE_A(1, 1); SBAR0();
    ISSUE_A(2, 2); SBAR0();
    BLOAD(Be, 0);  SBAR0();
    PH_WAIT("8");
    SBAR0();
    __builtin_amdgcn_s_barrier();
    SBAR0();
    DSREAD_A(Ae, 0);

    // phase 0 (wait 6: A(1) = prologue ops 3-4; newer = A2(2) + B0(4))
    PHASE(1, 3, 0, "6", 1, 1, Ao, Bo, Ae, Be);

    // phases 1..28 (7 macro-iters x 4), steady wait = 10
#pragma unroll 1
    for (int q = 0; q < 7; ++q) {
        int p = 4 * q;
        PHASE(2, 0, p + 1, "10", 1, 1, Ae, Be, Ao, Bo);
        PHASE(3, 1, p + 2, "10", 1, 1, Ao, Bo, Ae, Be);
        PHASE(0, 2, p + 3, "10", 1, 1, Ae, Be, Ao, Bo);
        PHASE(1, 3, p + 4, "10", 1, 1, Ao, Bo, Ae, Be);
    }
    // peeled tail: phases 29..31 (phase 28 issued A-stage 31)
    PHASE(2, 0, 29, "10", 0, 1, Ae, Be, Ao, Bo);
    PHASE(3, 1, 30, "8",  0, 1, Ao, Bo, Ae, Be);
    PHASE(0, 2, 31, "0",  0, 0, Ae, Be, Ao, Bo);   // compute-only; drains

#undef PHASE
#undef MFMAS
#undef DSREAD_A
#undef BLOAD
#undef ISSUE_A

    // ---- split-K pair reduction (whole 64 KB ring; stages drained) ----
    // ALL acc indices compile-time constants (rule #20).
    // kh=0 donates fm{2,3}; kh=1 donates fm{0,1}; own = kept + partner.
    char* red = &Ls[0][0];
    const int pairbase = s * 16384;
    if (kh == 0) {
#pragma unroll
        for (int fml = 0; fml < 2; ++fml)
#pragma unroll
            for (int fn = 0; fn < 4; ++fn)
                *(f32x4*)&red[pairbase + (fml * 4 + fn) * 1024 + lane * 16] =
                    acc[2 + fml][fn];
    } else {
#pragma unroll
        for (int fml = 0; fml < 2; ++fml)
#pragma unroll
            for (int fn = 0; fn < 4; ++fn)
                *(f32x4*)&red[pairbase + 8192 + (fml * 4 + fn) * 1024 +
                              lane * 16] = acc[fml][fn];
    }
    __syncthreads();
    f32x4 own[2][4];
    if (kh == 0) {
#pragma unroll
        for (int fml = 0; fml < 2; ++fml)
#pragma unroll
            for (int fn = 0; fn < 4; ++fn)
                own[fml][fn] = acc[fml][fn] + *(const f32x4*)&red[pairbase +
                    8192 + (fml * 4 + fn) * 1024 + lane * 16];
    } else {
#pragma unroll
        for (int fml = 0; fml < 2; ++fml)
#pragma unroll
            for (int fn = 0; fn < 4; ++fn)
                own[fml][fn] = acc[2 + fml][fn] + *(const f32x4*)&red[pairbase +
                    (fml * 4 + fn) * 1024 + lane * 16];
    }
    __syncthreads();   // reduction reads done before transpose overwrites

    // ---- epilogue on OWNED rows: z += Whx*x + bh; tanh; transpose ----
    // acc layout (16x16x32): col = lane&15, row = quad*4 + reg [m89-verified]
    // Owned global fm = kh*2 + fml (address math only; own[] is static-idx).
    // Transpose scratch: wave-private 32 rows x 128 B at flat + w*2048.
    bf16* Lw = (bf16*)&Ls[0][0] + (size_t)w * 2048;
#pragma unroll
    for (int fml = 0; fml < 2; ++fml) {
        int rb = bm0 + qm * 64 + (kh * 2 + fml) * 16 + quad * 4;
        float xv[4];
#pragma unroll
        for (int r = 0; r < 4; ++r) xv[r] = x[(size_t)(rb + r) * TT + t];
#pragma unroll
        for (int fn = 0; fn < 4; ++fn) {
            int col = cn0 + fn * 16 + lrow;
            float wx = Whx[col], bb = bh[col];
            int cbyte = (fn * 16 + lrow) * 2;
#pragma unroll
            for (int r = 0; r < 4; ++r) {
                int row_l = fml * 16 + quad * 4 + r;
                float z = own[fml][fn][r] + wx * xv[r] + bb;
                *(bf16*)((char*)Lw + row_l * 128 +
                         (cbyte ^ ((row_l & 7) << 4))) = (bf16)tanhf(z);
            }
        }
    }
    // read own wave's tile in frag-slot order; 16B coalesced global stores.
#pragma unroll
    for (int fml = 0; fml < 2; ++fml) {
#pragma unroll
        for (int kc = 0; kc < 2; ++kc) {
            int row_l = fml * 16 + lrow;
            int cb    = (kc * 64 + quad * 16) ^ ((row_l & 7) << 4);
            bf16x8 v = *(const bf16x8*)((const char*)Lw + row_l * 128 + cb);
            size_t sub = (size_t)((bm0 >> 4) + qm * 4 + kh * 2 + fml) * 64 +
                         (cn0 >> 5) + kc;
            *(bf16x8*)(Sw + (sub * 64 + lane) * 8) = v;
        }
    }
}

// ---------------------------------------------------------------------------
// out[b,c] = sum_h Why[h,c] * S[b,h] + bp[c]   (S frag-major)
// ---------------------------------------------------------------------------
__global__ void out_proj(const bf16* __restrict__ S,
                         const float* __restrict__ Why,   // [H, C]
                         const float* __restrict__ bp,    // [C]
                         float* __restrict__ out) {       // [B, C]
    int b = blockIdx.x, tid = threadIdx.x;
    int h0 = tid * 8;                                     // 256*8 = H exactly
    size_t sub  = (size_t)(b >> 4) * 64 + (h0 >> 5);
    size_t slot = (size_t)(b & 15) | (size_t)(((h0 >> 3) & 3) << 4);
    bf16x8 v = *(const bf16x8*)(S + (sub * 64 + slot) * 8);
    float p[NC];
#pragma unroll
    for (int c = 0; c < NC; ++c) p[c] = 0.f;
#pragma unroll
    for (int j = 0; j < 8; ++j) {
        float s = (float)v[j];
        const float* wr = Why + (size_t)(h0 + j) * NC;
#pragma unroll
        for (int c = 0; c < NC; ++c) p[c] += s * wr[c];
    }
    __shared__ float red[256 * NC];
#pragma unroll
    for (int c = 0; c < NC; ++c) red[tid * NC + c] = p[c];
    __syncthreads();
    for (int s = 128; s > 0; s >>= 1) {
        if (tid < s)
#pragma unroll
            for (int c = 0; c < NC; ++c) red[tid * NC + c] += red[(tid + s) * NC + c];
        __syncthreads();
    }
    if (tid < NC) out[(size_t)b * NC + tid] = red[tid] + bp[tid];
}

// ---------------------------------------------------------------------------
extern "C" void kernel_launch(void* const* d_in, const int* in_sizes, int n_in,
                              void* d_out, int out_size, void* d_ws, size_t ws_size,
                              hipStream_t stream) {
    const float* x   = (const float*)d_in[0];   // [B, T]
    const float* Whx = (const float*)d_in[1];   // [H, 1]
    const float* Whh = (const float*)d_in[2];   // [H, H]
    const float* Why = (const float*)d_in[3];   // [H, C]
    const float* bh  = (const float*)d_in[4];   // [H, 1]
    const float* bp  = (const float*)d_in[5];   // [C, 1]
    float* out = (float*)d_out;

    // workspace: Wshuf (8 MB) | S0 (8 MB) | S1 (8 MB)   (all frag-major)
    bf16* Wshuf = (bf16*)d_ws;
    bf16* S0 = (bf16*)((char*)d_ws + (size_t)8 * 1024 * 1024);
    bf16* S1 = (bf16*)((char*)d_ws + (size_t)16 * 1024 * 1024);

    hipLaunchKernelGGL(w_shuffle_kernel, dim3((H * H / 8) / 256), dim3(256),
                       0, stream, Whh, Wshuf);

    // t = 0 writes S1; step t reads (t&1 ? S1 : S0), writes the other.
    hipLaunchKernelGGL(rnn_init, dim3(BB), dim3(256), 0, stream, x, Whx, bh, S1);

    for (int t = 1; t < TT; ++t) {
        const bf16* Srd = (t & 1) ? S1 : S0;
        bf16*       Swr = (t & 1) ? S0 : S1;
        hipLaunchKernelGGL(rnn_step, dim3(256), dim3(512), 0, stream,
                           x, Whx, bh, Wshuf, Srd, Swr, t);
    }

    // t=63 (odd) wrote S0
    hipLaunchKernelGGL(out_proj, dim3(BB), dim3(256), 0, stream, S0, Why, bp, out);
}

// Round 11
// 1719.582 us; speedup vs baseline: 1.0058x; 1.0058x over previous
//
#include <hip/hip_runtime.h>
#include <cstdint>
#include <cstddef>
#include <cmath>

#define H  2048
#define BB 2048   // batch
#define TT 64     // time steps
#define NC 10     // classes

typedef __bf16 bf16;
typedef bf16  bf16x8 __attribute__((ext_vector_type(8)));
typedef float f32x4  __attribute__((ext_vector_type(4)));

// ---------------------------------------------------------------------------
// async global->LDS, 16B per lane. LDS dest is wave-uniform base + lane*16;
// global source is per-lane.
// ---------------------------------------------------------------------------
__device__ __forceinline__ void load_lds16(const void* g, void* l) {
    __builtin_amdgcn_global_load_lds(
        (__attribute__((address_space(1))) void*)(void*)g,
        (__attribute__((address_space(3))) void*)l,
        16, 0, 0);
}

// ---------------------------------------------------------------------------
// FRAG-MAJOR layout (W_hh and S, since R12).
// For a matrix [R rows][H k-cols] (bf16):
//   subtile (r16, k32) = 16 rows x 32 k = 1024 B at id = r16*(H/32) + k32.
//   lane-slot l (16 B) holds M[r16*16 + (l&15)][k32*32 + (l>>4)*8 .. +8]
// = exactly the v_mfma_f32_16x16x32_bf16 A/B fragment, so a wave's frag load
// is ONE coalesced 1 KB segment: base + id*512 + lane*8 (bf16 elems).
// ---------------------------------------------------------------------------
__global__ void w_shuffle_kernel(const float* __restrict__ Whh,
                                 bf16* __restrict__ Wshuf) {
    int tid = blockIdx.x * blockDim.x + threadIdx.x;   // 0 .. H*H/8-1
    int sub = tid >> 6;          // subtile id
    int l   = tid & 63;          // dest lane slot
    int n16 = sub >> 6;          // 0..127
    int k32 = sub & 63;          // 0..63
    int n = n16 * 16 + (l & 15);
    int k = k32 * 32 + (l >> 4) * 8;
    const float* src = Whh + (size_t)n * H + k;
    bf16x8 o;
#pragma unroll
    for (int j = 0; j < 8; ++j) o[j] = (bf16)src[j];
    *(bf16x8*)(Wshuf + (size_t)tid * 8) = o;
}

// ---------------------------------------------------------------------------
// t = 0: S[b,i] = tanh(Whx[i]*x[b,0] + bh[i]), written FRAG-MAJOR.
// ---------------------------------------------------------------------------
__global__ void rnn_init(const float* __restrict__ x,     // [B, T]
                         const float* __restrict__ Whx,   // [H]
                         const float* __restrict__ bh,    // [H]
                         bf16* __restrict__ S) {          // frag-major
    int b  = blockIdx.x;
    int i0 = threadIdx.x * 8;
    float xv = x[(size_t)b * TT];
    bf16x8 o;
#pragma unroll
    for (int j = 0; j < 8; ++j)
        o[j] = (bf16)tanhf(Whx[i0 + j] * xv + bh[i0 + j]);
    size_t sub  = (size_t)(b >> 4) * 64 + (i0 >> 5);
    size_t slot = (size_t)(b & 15) | (size_t)(((i0 >> 3) & 3) << 4);
    *(bf16x8*)(S + (sub * 64 + slot) * 8) = o;
}

// ---------------------------------------------------------------------------
// One RNN time step, Round-21 = Round-20 + __launch_bounds__(512, 2):
//   Sw[b,i] = tanh( sum_k Sr[b,k]*W[i,k] + Whx[i]*x[b,t] + bh[i] )
//
// R20 post-mortem: __launch_bounds__(512) WITHOUT the min-waves arg let
// hipcc's occupancy heuristic cap the kernel at 88 VGPRs; live state is
// ~150+ (acc 64 + 4 frag banks 64 + addressing) -> ~64 regs spilled to
// scratch; profiled dispatch showed the thrash (40 ms, MfmaUtil 1.9%).
// The B-over-VMEM architecture was never actually measured. R21 pins
// (512, 2) -> VGPR cap 256, zero spill. Nothing else changed.
//
// Architecture (from R20):
//   - B fragments load reg-direct over the VMEM pipe from the XCD-L2-
//     resident W panel (XCD-owns-n; 1 KB coalesced wave segments; 2x dup).
//   - A stays on gload_lds + LDS: 4 x 16 KB ring, per-phase 2 stage ops.
//     Per-phase pipe budget: LDS ~544 cy, VMEM ~857 cy, MFMA 620 cy.
//   - R19 read-ahead pipeline: fragments for phase p+1 load during phase
//     p's MFMAs (ping-pong banks, static names). Counted vmcnt guards the
//     A ring: per phase 6 vmcnt ops (2 A-stage + 4 B) -> steady wait 10.
//   - Split-K pair reduction + 8-wave epilogue (R18) -> absmax 2.44e-4.
// ---------------------------------------------------------------------------
#define PH_WAIT(NSTR) asm volatile("s_waitcnt vmcnt(" NSTR ")" ::: "memory")
#define SBAR0()       __builtin_amdgcn_sched_barrier(0)

__launch_bounds__(512, 2)
__global__ void rnn_step(const float* __restrict__ x,     // [B, T]
                         const float* __restrict__ Whx,   // [H]
                         const float* __restrict__ bh,    // [H]
                         const bf16*  __restrict__ Wshuf, // frag-major W_hh
                         const bf16*  __restrict__ Sr,    // frag-major S read
                         bf16* __restrict__ Sw,           // frag-major S write
                         int t) {
    // A ring slot = 16 segs x 1 KB: segs 0..7 = chunk-lo m16 0..7,
    //                               segs 8..15 = chunk-hi m16 0..7.
    __shared__ __align__(16) char Ls[4][16384];   // 64 KB

    const int tid  = threadIdx.x;
    const int w    = tid >> 6;          // wave 0..7
    const int lane = tid & 63;
    const int lrow = lane & 15;
    const int quad = lane >> 4;

    // XCD-owns-n mapping: XCD x covers n-cols [x*256, x*256+256).
    const int xcd = blockIdx.x & 7;
    const int loc = blockIdx.x >> 3;               // 0..31
    const int bm0 = (loc >> 1) * 128;              // batch-row tile origin
    const int bn0 = xcd * 256 + (loc & 1) * 128;   // hidden-col tile origin

    const int kh   = w >> 2;                       // K-half (0: k<1024)
    const int s    = w & 3;                        // quadrant id
    const int qm   = s & 1;                        // m-quadrant (64 rows)
    const int qn   = s >> 1;                       // n-quadrant (64 cols)
    const int cn0  = bn0 + qn * 64;                // wave's first col

    // A staging source: wave w owns A m16 subtile (bm0>>4)+w, both k-halves.
    const char* srcA = (const char*)Sr +
        ((size_t)((bm0 >> 4) + w) * 64) * 1024 + (size_t)lane * 16;
    // B reg-load base: block's n16 panel start, per-lane +lane*16B.
    const char* srcB = (const char*)Wshuf +
        ((size_t)(bn0 >> 4) * 64) * 1024 + (size_t)lane * 16;

    f32x4 acc[4][4];
#pragma unroll
    for (int i = 0; i < 4; ++i)
#pragma unroll
        for (int j = 0; j < 4; ++j) acc[i][j] = (f32x4){0.f, 0.f, 0.f, 0.f};

    // fragment ping-pong banks (static names; rule #20)
    bf16x8 Ae[4], Be[4], Ao[4], Bo[4];

    // ---- A-stage for phase pp into ring slot RI (2 VMEM ops) ----
#define ISSUE_A(RI, pp)                                                      \
    {                                                                        \
        load_lds16(srcA + (size_t)(pp) * 1024,        &Ls[RI][w * 1024]);    \
        load_lds16(srcA + (size_t)(32 + (pp)) * 1024, &Ls[RI][(8 + w) * 1024]); \
    }

    // ---- B reg-loads for phase pp into bank Bx (4 VMEM ops, 1 KB each) ----
#define BLOAD(Bx, pp)                                                        \
    {                                                                        \
        _Pragma("unroll")                                                    \
        for (int fn = 0; fn < 4; ++fn)                                       \
            Bx[fn] = *(const bf16x8*)(srcB +                                 \
                ((size_t)(qn * 4 + fn) * 64 + 32 * kh + (pp)) * 1024);       \
    }

    // ---- A fragment ds_reads of ring slot RI into bank Ax (4 ops) ----
#define DSREAD_A(Ax, RI)                                                     \
    {                                                                        \
        _Pragma("unroll")                                                    \
        for (int fm = 0; fm < 4; ++fm)                                       \
            Ax[fm] = *(const bf16x8*)&Ls[RI]                                 \
                [(kh * 8 + qm * 4 + fm) * 1024 + lane * 16];                 \
    }

    // ---- 16 MFMAs on bank (Ax, Bx) ----
#define MFMAS(Ax, Bx)                                                        \
    {                                                                        \
        __builtin_amdgcn_s_setprio(1);                                       \
        _Pragma("unroll")                                                    \
        for (int fm = 0; fm < 4; ++fm)                                       \
            _Pragma("unroll")                                                \
            for (int fn = 0; fn < 4; ++fn)                                   \
                acc[fm][fn] = __builtin_amdgcn_mfma_f32_16x16x32_bf16(       \
                    Ax[fm], Bx[fn], acc[fm][fn], 0, 0, 0);                   \
        __builtin_amdgcn_s_setprio(0);                                       \
    }

    // phase p: wait W (A-stage p+1 resident), barrier, issue A-stage p+3,
    // load B(p+1) regs + ds_read A(p+1) slot, MFMA on current banks.
#define PHASE(RNext, RIss, p, W, DOISS, DOREAD, AN, BN, AC, BC)              \
    {                                                                        \
        PH_WAIT(W);                                                          \
        SBAR0();                                                             \
        __builtin_amdgcn_s_barrier();                                        \
        SBAR0();                                                             \
        if (DOISS) ISSUE_A(RIss, (p) + 3);                                   \
        if (DOREAD) { BLOAD(BN, (p) + 1); DSREAD_A(AN, RNext); }             \
        MFMAS(AC, BC);                                                       \
    }

    // prologue: A-stages 0,1,2 (ops 1-6); B(0) (ops 7-10); wait A(0)
    // (8 newer ops in flight); barrier; pre-read slot 0.
    ISSUE_A(0, 0); SBAR0();
    ISSUE_A(1, 1); SBAR0();
    ISSUE_A(2, 2); SBAR0();
    BLOAD(Be, 0);  SBAR0();
    PH_WAIT("8");
    SBAR0();
    __builtin_amdgcn_s_barrier();
    SBAR0();
    DSREAD_A(Ae, 0);

    // phase 0 (wait 6: A(1) = prologue ops 3-4; newer = A2(2) + B0(4))
    PHASE(1, 3, 0, "6", 1, 1, Ao, Bo, Ae, Be);

    // phases 1..28 (7 macro-iters x 4), steady wait = 10
#pragma unroll 1
    for (int q = 0; q < 7; ++q) {
        int p = 4 * q;
        PHASE(2, 0, p + 1, "10", 1, 1, Ae, Be, Ao, Bo);
        PHASE(3, 1, p + 2, "10", 1, 1, Ao, Bo, Ae, Be);
        PHASE(0, 2, p + 3, "10", 1, 1, Ae, Be, Ao, Bo);
        PHASE(1, 3, p + 4, "10", 1, 1, Ao, Bo, Ae, Be);
    }
    // peeled tail: phases 29..31 (phase 28 issued A-stage 31)
    PHASE(2, 0, 29, "10", 0, 1, Ae, Be, Ao, Bo);
    PHASE(3, 1, 30, "8",  0, 1, Ao, Bo, Ae, Be);
    PHASE(0, 2, 31, "0",  0, 0, Ae, Be, Ao, Bo);   // compute-only; drains

#undef PHASE
#undef MFMAS
#undef DSREAD_A
#undef BLOAD
#undef ISSUE_A

    // ---- split-K pair reduction (whole 64 KB ring; stages drained) ----
    // ALL acc indices compile-time constants (rule #20).
    // kh=0 donates fm{2,3}; kh=1 donates fm{0,1}; own = kept + partner.
    char* red = &Ls[0][0];
    const int pairbase = s * 16384;
    if (kh == 0) {
#pragma unroll
        for (int fml = 0; fml < 2; ++fml)
#pragma unroll
            for (int fn = 0; fn < 4; ++fn)
                *(f32x4*)&red[pairbase + (fml * 4 + fn) * 1024 + lane * 16] =
                    acc[2 + fml][fn];
    } else {
#pragma unroll
        for (int fml = 0; fml < 2; ++fml)
#pragma unroll
            for (int fn = 0; fn < 4; ++fn)
                *(f32x4*)&red[pairbase + 8192 + (fml * 4 + fn) * 1024 +
                              lane * 16] = acc[fml][fn];
    }
    __syncthreads();
    f32x4 own[2][4];
    if (kh == 0) {
#pragma unroll
        for (int fml = 0; fml < 2; ++fml)
#pragma unroll
            for (int fn = 0; fn < 4; ++fn)
                own[fml][fn] = acc[fml][fn] + *(const f32x4*)&red[pairbase +
                    8192 + (fml * 4 + fn) * 1024 + lane * 16];
    } else {
#pragma unroll
        for (int fml = 0; fml < 2; ++fml)
#pragma unroll
            for (int fn = 0; fn < 4; ++fn)
                own[fml][fn] = acc[2 + fml][fn] + *(const f32x4*)&red[pairbase +
                    (fml * 4 + fn) * 1024 + lane * 16];
    }
    __syncthreads();   // reduction reads done before transpose overwrites

    // ---- epilogue on OWNED rows: z += Whx*x + bh; tanh; transpose ----
    // acc layout (16x16x32): col = lane&15, row = quad*4 + reg [m89-verified]
    // Owned global fm = kh*2 + fml (address math only; own[] is static-idx).
    // Transpose scratch: wave-private 32 rows x 128 B at flat + w*2048.
    bf16* Lw = (bf16*)&Ls[0][0] + (size_t)w * 2048;
#pragma unroll
    for (int fml = 0; fml < 2; ++fml) {
        int rb = bm0 + qm * 64 + (kh * 2 + fml) * 16 + quad * 4;
        float xv[4];
#pragma unroll
        for (int r = 0; r < 4; ++r) xv[r] = x[(size_t)(rb + r) * TT + t];
#pragma unroll
        for (int fn = 0; fn < 4; ++fn) {
            int col = cn0 + fn * 16 + lrow;
            float wx = Whx[col], bb = bh[col];
            int cbyte = (fn * 16 + lrow) * 2;
#pragma unroll
            for (int r = 0; r < 4; ++r) {
                int row_l = fml * 16 + quad * 4 + r;
                float z = own[fml][fn][r] + wx * xv[r] + bb;
                *(bf16*)((char*)Lw + row_l * 128 +
                         (cbyte ^ ((row_l & 7) << 4))) = (bf16)tanhf(z);
            }
        }
    }
    // read own wave's tile in frag-slot order; 16B coalesced global stores.
#pragma unroll
    for (int fml = 0; fml < 2; ++fml) {
#pragma unroll
        for (int kc = 0; kc < 2; ++kc) {
            int row_l = fml * 16 + lrow;
            int cb    = (kc * 64 + quad * 16) ^ ((row_l & 7) << 4);
            bf16x8 v = *(const bf16x8*)((const char*)Lw + row_l * 128 + cb);
            size_t sub = (size_t)((bm0 >> 4) + qm * 4 + kh * 2 + fml) * 64 +
                         (cn0 >> 5) + kc;
            *(bf16x8*)(Sw + (sub * 64 + lane) * 8) = v;
        }
    }
}

// ---------------------------------------------------------------------------
// out[b,c] = sum_h Why[h,c] * S[b,h] + bp[c]   (S frag-major)
// ---------------------------------------------------------------------------
__global__ void out_proj(const bf16* __restrict__ S,
                         const float* __restrict__ Why,   // [H, C]
                         const float* __restrict__ bp,    // [C]
                         float* __restrict__ out) {       // [B, C]
    int b = blockIdx.x, tid = threadIdx.x;
    int h0 = tid * 8;                                     // 256*8 = H exactly
    size_t sub  = (size_t)(b >> 4) * 64 + (h0 >> 5);
    size_t slot = (size_t)(b & 15) | (size_t)(((h0 >> 3) & 3) << 4);
    bf16x8 v = *(const bf16x8*)(S + (sub * 64 + slot) * 8);
    float p[NC];
#pragma unroll
    for (int c = 0; c < NC; ++c) p[c] = 0.f;
#pragma unroll
    for (int j = 0; j < 8; ++j) {
        float s = (float)v[j];
        const float* wr = Why + (size_t)(h0 + j) * NC;
#pragma unroll
        for (int c = 0; c < NC; ++c) p[c] += s * wr[c];
    }
    __shared__ float red[256 * NC];
#pragma unroll
    for (int c = 0; c < NC; ++c) red[tid * NC + c] = p[c];
    __syncthreads();
    for (int s = 128; s > 0; s >>= 1) {
        if (tid < s)
#pragma unroll
            for (int c = 0; c < NC; ++c) red[tid * NC + c] += red[(tid + s) * NC + c];
        __syncthreads();
    }
    if (tid < NC) out[(size_t)b * NC + tid] = red[tid] + bp[tid];
}

// ---------------------------------------------------------------------------
extern "C" void kernel_launch(void* const* d_in, const int* in_sizes, int n_in,
                              void* d_out, int out_size, void* d_ws, size_t ws_size,
                              hipStream_t stream) {
    const float* x   = (const float*)d_in[0];   // [B, T]
    const float* Whx = (const float*)d_in[1];   // [H, 1]
    const float* Whh = (const float*)d_in[2];   // [H, H]
    const float* Why = (const float*)d_in[3];   // [H, C]
    const float* bh  = (const float*)d_in[4];   // [H, 1]
    const float* bp  = (const float*)d_in[5];   // [C, 1]
    float* out = (float*)d_out;

    // workspace: Wshuf (8 MB) | S0 (8 MB) | S1 (8 MB)   (all frag-major)
    bf16* Wshuf = (bf16*)d_ws;
    bf16* S0 = (bf16*)((char*)d_ws + (size_t)8 * 1024 * 1024);
    bf16* S1 = (bf16*)((char*)d_ws + (size_t)16 * 1024 * 1024);

    hipLaunchKernelGGL(w_shuffle_kernel, dim3((H * H / 8) / 256), dim3(256),
                       0, stream, Whh, Wshuf);

    // t = 0 writes S1; step t reads (t&1 ? S1 : S0), writes the other.
    hipLaunchKernelGGL(rnn_init, dim3(BB), dim3(256), 0, stream, x, Whx, bh, S1);

    for (int t = 1; t < TT; ++t) {
        const bf16* Srd = (t & 1) ? S1 : S0;
        bf16*       Swr = (t & 1) ? S0 : S1;
        hipLaunchKernelGGL(rnn_step, dim3(256), dim3(512), 0, stream,
                           x, Whx, bh, Wshuf, Srd, Swr, t);
    }

    // t=63 (odd) wrote S0
    hipLaunchKernelGGL(out_proj, dim3(BB), dim3(256), 0, stream, S0, Why, bp, out);
}

// Round 12
// 1615.379 us; speedup vs baseline: 1.0707x; 1.0645x over previous
//
#include <hip/hip_runtime.h>
#include <cstdint>
#include <cstddef>
#include <cmath>

#define H  2048
#define BB 2048   // batch
#define TT 64     // time steps
#define NC 10     // classes

typedef __bf16 bf16;
typedef bf16  bf16x8 __attribute__((ext_vector_type(8)));
typedef float f32x4  __attribute__((ext_vector_type(4)));

// ---------------------------------------------------------------------------
// async global->LDS, 16B per lane. LDS dest is wave-uniform base + lane*16;
// global source is per-lane.
// ---------------------------------------------------------------------------
__device__ __forceinline__ void load_lds16(const void* g, void* l) {
    __builtin_amdgcn_global_load_lds(
        (__attribute__((address_space(1))) void*)(void*)g,
        (__attribute__((address_space(3))) void*)l,
        16, 0, 0);
}

// ---------------------------------------------------------------------------
// FRAG-MAJOR layout (W_hh and S, since R12).
// For a matrix [R rows][H k-cols] (bf16):
//   subtile (r16, k32) = 16 rows x 32 k = 1024 B at id = r16*(H/32) + k32.
//   lane-slot l (16 B) holds M[r16*16 + (l&15)][k32*32 + (l>>4)*8 .. +8]
// = exactly the v_mfma_f32_16x16x32_bf16 A/B fragment, so a wave's frag load
// is ONE coalesced 1 KB segment: base + id*512 + lane*8 (bf16 elems).
// ---------------------------------------------------------------------------
__global__ void w_shuffle_kernel(const float* __restrict__ Whh,
                                 bf16* __restrict__ Wshuf) {
    int tid = blockIdx.x * blockDim.x + threadIdx.x;   // 0 .. H*H/8-1
    int sub = tid >> 6;          // subtile id
    int l   = tid & 63;          // dest lane slot
    int n16 = sub >> 6;          // 0..127
    int k32 = sub & 63;          // 0..63
    int n = n16 * 16 + (l & 15);
    int k = k32 * 32 + (l >> 4) * 8;
    const float* src = Whh + (size_t)n * H + k;
    bf16x8 o;
#pragma unroll
    for (int j = 0; j < 8; ++j) o[j] = (bf16)src[j];
    *(bf16x8*)(Wshuf + (size_t)tid * 8) = o;
}

// ---------------------------------------------------------------------------
// t = 0: S[b,i] = tanh(Whx[i]*x[b,0] + bh[i]), written FRAG-MAJOR.
// ---------------------------------------------------------------------------
__global__ void rnn_init(const float* __restrict__ x,     // [B, T]
                         const float* __restrict__ Whx,   // [H]
                         const float* __restrict__ bh,    // [H]
                         bf16* __restrict__ S) {          // frag-major
    int b  = blockIdx.x;
    int i0 = threadIdx.x * 8;
    float xv = x[(size_t)b * TT];
    bf16x8 o;
#pragma unroll
    for (int j = 0; j < 8; ++j)
        o[j] = (bf16)tanhf(Whx[i0 + j] * xv + bh[i0 + j]);
    size_t sub  = (size_t)(b >> 4) * 64 + (i0 >> 5);
    size_t slot = (size_t)(b & 15) | (size_t)(((i0 >> 3) & 3) << 4);
    *(bf16x8*)(S + (sub * 64 + slot) * 8) = o;
}

// ---------------------------------------------------------------------------
// One RNN time step, Round-22 "128x64 wave tiles, 4-way split-K, parity
// phases" (base = R19, the 1412us best; R20/R21 B-over-VMEM refuted):
//   Sw[b,i] = tanh( sum_k Sr[b,k]*W[i,k] + Whx[i]*x[b,t] + bh[i] )
//
// R19 wall: 64 ds_read_b128 + stage writes ~ 1100 cy/phase > MFMA 620.
// Reads/MFMA is set by wave-tile shape: 64x64 -> 0.5; 128x64 -> 0.375.
//
//   - 8 waves, wave w = (nq = w&1: 64-col half, kq = w>>1: 512-k quarter).
//     Wave tile 128 x 64: acc[8][4] f32x4 = 128 VGPR. 4-way split-K.
//   - 32 phases. Phase p serves quarter-PAIR (p&1): quarters {0,1} on even
//     phases, {2,3} on odd; chunk c = p>>1. Ring slot (32 KB) = A 2x8 segs
//     + B 2x8 segs for the pair; 4-slot ring = 128 KB exactly.
//   - ACTIVE waves (kq>>1 == p&1) run 32 MFMAs; INACTIVE waves use the
//     phase to DSREAD their next-phase fragments (single bank, read one
//     full phase ahead -> LDS latency fully hidden). Waves w and w+4 share
//     a SIMD with opposite parity -> every SIMD computes every phase.
//   - Per-phase: LDS 48 reads (576cy) + 32 KB writes (256cy) = 832cy;
//     MFMA 620cy; VMEM 32 KB (571cy). Counted vmcnt: 4 stage ops/wave/
//     phase; steady wait vmcnt(4) (stage(p+1) complete, stage(p+2)'s 4 ops
//     newer); NEVER 0 in-loop; tail 4/4/0/0. Slot safety: ISSUE(p+3)
//     writes slot (p-1)&3, last read at phase p-2, two barriers back.
//   - Split-K reduction: round 1 kq1->kq0, kq3->kq2 (full 32 KB donations,
//     4 regions = 128 KB); round 2 redistributes so EVERY wave owns a
//     32x64 row-slab -> 8-wave-parallel tanh epilogue. All acc indices
//     literal (rule #20). __launch_bounds__(512,2) pinned (R20 lesson).
// ---------------------------------------------------------------------------
#define PH_WAIT(NSTR) asm volatile("s_waitcnt vmcnt(" NSTR ")" ::: "memory")
#define SBAR0()       __builtin_amdgcn_sched_barrier(0)

__launch_bounds__(512, 2)
__global__ void rnn_step(const float* __restrict__ x,     // [B, T]
                         const float* __restrict__ Whx,   // [H]
                         const float* __restrict__ bh,    // [H]
                         const bf16*  __restrict__ Wshuf, // frag-major W_hh
                         const bf16*  __restrict__ Sr,    // frag-major S read
                         bf16* __restrict__ Sw,           // frag-major S write
                         int t) {
    // ring slot = 32 segs x 1 KB:
    //   segs  0..7  = A m16 0..7 (quarter qa)   segs  8..15 = A (quarter qb)
    //   segs 16..23 = B n16 0..7 (quarter qa)   segs 24..31 = B (quarter qb)
    // where (qa, qb) = (2*(p&1), 2*(p&1)+1) for the phase p the slot serves.
    __shared__ __align__(16) char Ls[4][32768];   // 128 KB -> 1 block/CU

    const int tid  = threadIdx.x;
    const int w    = tid >> 6;          // wave 0..7
    const int lane = tid & 63;
    const int lrow = lane & 15;
    const int quad = lane >> 4;

    // XCD-owns-n mapping: XCD x covers n-cols [x*256, x*256+256).
    const int xcd = blockIdx.x & 7;
    const int loc = blockIdx.x >> 3;               // 0..31
    const int bm0 = (loc >> 1) * 128;              // batch-row tile origin
    const int bn0 = xcd * 256 + (loc & 1) * 128;   // hidden-col tile origin

    const int nq  = w & 1;                         // n-half (64 cols)
    const int kq  = w >> 1;                        // k-quarter (512 k)
    const int khi = kq >> 1;                       // parity group
    const int dlt = kq & 1;                        // index within pair
    const int cn0 = bn0 + nq * 64;                 // wave's first col

    // staging sources (per wave): wave w owns A m16 subtile (bm0>>4)+w and
    // B n16 subtile (bn0>>4)+w. 1 KB per k32 chunk, per-lane +lane*16B.
    const char* srcA = (const char*)Sr +
        ((size_t)((bm0 >> 4) + w) * 64) * 1024 + (size_t)lane * 16;
    const char* srcB = (const char*)Wshuf +
        ((size_t)((bn0 >> 4) + w) * 64) * 1024 + (size_t)lane * 16;

    f32x4 acc[8][4];
#pragma unroll
    for (int i = 0; i < 8; ++i)
#pragma unroll
        for (int j = 0; j < 4; ++j) acc[i][j] = (f32x4){0.f, 0.f, 0.f, 0.f};

    // single fragment bank (read one phase ahead during inactive phases)
    bf16x8 Af[8], Bf[4];

    // ---- stage phase pp's pair into ring slot RI (4 VMEM ops) ----
#define ISSUE(RI, pp)                                                        \
    {                                                                        \
        const int qa_ = 2 * ((pp) & 1);                                      \
        const int cc_ = (pp) >> 1;                                           \
        load_lds16(srcA + (size_t)(qa_ * 16 + cc_) * 1024,                   \
                   &Ls[RI][w * 1024]);                                       \
        load_lds16(srcA + (size_t)((qa_ + 1) * 16 + cc_) * 1024,             \
                   &Ls[RI][(8 + w) * 1024]);                                 \
        load_lds16(srcB + (size_t)(qa_ * 16 + cc_) * 1024,                   \
                   &Ls[RI][(16 + w) * 1024]);                                \
        load_lds16(srcB + (size_t)((qa_ + 1) * 16 + cc_) * 1024,             \
                   &Ls[RI][(24 + w) * 1024]);                                \
    }

    // ---- read own fragments from ring slot RI into the bank (12 ops) ----
#define DSREAD(RI)                                                           \
    {                                                                        \
        _Pragma("unroll")                                                    \
        for (int fm = 0; fm < 8; ++fm)                                       \
            Af[fm] = *(const bf16x8*)&Ls[RI]                                 \
                [(dlt * 8 + fm) * 1024 + lane * 16];                         \
        _Pragma("unroll")                                                    \
        for (int fn = 0; fn < 4; ++fn)                                       \
            Bf[fn] = *(const bf16x8*)&Ls[RI]                                 \
                [(16 + dlt * 8 + nq * 4 + fn) * 1024 + lane * 16];           \
    }

    // ---- 32 MFMAs on the bank ----
#define MFMAS()                                                              \
    {                                                                        \
        __builtin_amdgcn_s_setprio(1);                                       \
        _Pragma("unroll")                                                    \
        for (int fm = 0; fm < 8; ++fm)                                       \
            _Pragma("unroll")                                                \
            for (int fn = 0; fn < 4; ++fn)                                   \
                acc[fm][fn] = __builtin_amdgcn_mfma_f32_16x16x32_bf16(       \
                    Af[fm], Bf[fn], acc[fm][fn], 0, 0, 0);                   \
        __builtin_amdgcn_s_setprio(0);                                       \
    }

    // phase p: wait W (stage(p+1) resident), barrier, issue stage(p+3);
    // active waves (khi == parity) compute; inactive read next fragments.
#define PHASE(RNext, RIss, p, W, DOISS, PARITY, DOREAD)                      \
    {                                                                        \
        PH_WAIT(W); SBAR0();                                                 \
        __builtin_amdgcn_s_barrier(); SBAR0();                               \
        if (DOISS) ISSUE(RIss, (p) + 3);                                     \
        if (khi == (PARITY)) { MFMAS(); }                                    \
        else if (DOREAD) { DSREAD(RNext); }                                  \
    }

    // prologue: stage phases 0,1,2 into slots 0,1,2; wait stage(0) (8 newer
    // ops in flight); barrier; even-parity waves pre-read slot 0.
    ISSUE(0, 0); SBAR0();
    ISSUE(1, 1); SBAR0();
    ISSUE(2, 2); SBAR0();
    PH_WAIT("8"); SBAR0();
    __builtin_amdgcn_s_barrier(); SBAR0();
    if (khi == 0) DSREAD(0);

    // main loop: phases 0..27 (7 macro-iters x 4), steady wait = 4
#pragma unroll 1
    for (int q = 0; q < 7; ++q) {
        int p = 4 * q;
        PHASE(1, 3, p + 0, "4", 1, 0, 1);
        PHASE(2, 0, p + 1, "4", 1, 1, 1);
        PHASE(3, 1, p + 2, "4", 1, 0, 1);
        PHASE(0, 2, p + 3, "4", 1, 1, 1);
    }
    // peeled tail: phases 28..31 (phase 28 issues stage 31)
    PHASE(1, 3, 28, "4", 1, 0, 1);
    PHASE(2, 0, 29, "4", 0, 1, 1);
    PHASE(3, 1, 30, "0", 0, 0, 1);
    PHASE(0, 2, 31, "0", 0, 1, 0);

#undef PHASE
#undef MFMAS
#undef DSREAD
#undef ISSUE

    // ---- 4-way split-K reduction (ring reused; all stages drained) ----
    // All acc indices are compile-time literals (rule #20).
    char* red = &Ls[0][0];
    // Round 1: kq1 -> kq0, kq3 -> kq2. Donor regions 32 KB:
    //   region(nq, kq>>1) = (nq*2 + (kq>>1)) * 32768.
    if (kq == 1 || kq == 3) {
        char* r0 = red + (size_t)(nq * 2 + khi) * 32768;
#pragma unroll
        for (int fm = 0; fm < 8; ++fm)
#pragma unroll
            for (int fn = 0; fn < 4; ++fn)
                *(f32x4*)&r0[((fm * 4 + fn) * 64 + lane) * 16] = acc[fm][fn];
    }
    __syncthreads();
    if (kq == 0 || kq == 2) {
        const char* r0 = red + (size_t)(nq * 2 + khi) * 32768;
#pragma unroll
        for (int fm = 0; fm < 8; ++fm)
#pragma unroll
            for (int fn = 0; fn < 4; ++fn)
                acc[fm][fn] += *(const f32x4*)&r0[((fm * 4 + fn) * 64 + lane) * 16];
    }
    __syncthreads();
    // Round 2: redistribute so kq_j owns fm pair {2j, 2j+1}.
    //   kq0 (holds s01) donates parts P0=fm{2,3}, P1=fm{4,5}, P2=fm{6,7}
    //   kq2 (holds s23) donates parts P0=fm{0,1}, P1=fm{2,3}, P2=fm{6,7}
    //   region(nq, src = kq>>1) = (nq*2 + src) * 24576; part P at +P*8192.
    if (kq == 0) {
        char* r2 = red + (size_t)(nq * 2 + 0) * 24576;
#pragma unroll
        for (int fml = 0; fml < 2; ++fml)
#pragma unroll
            for (int fn = 0; fn < 4; ++fn) {
                *(f32x4*)&r2[0 * 8192 + ((fml * 4 + fn) * 64 + lane) * 16] = acc[2 + fml][fn];
                *(f32x4*)&r2[1 * 8192 + ((fml * 4 + fn) * 64 + lane) * 16] = acc[4 + fml][fn];
                *(f32x4*)&r2[2 * 8192 + ((fml * 4 + fn) * 64 + lane) * 16] = acc[6 + fml][fn];
            }
    } else if (kq == 2) {
        char* r2 = red + (size_t)(nq * 2 + 1) * 24576;
#pragma unroll
        for (int fml = 0; fml < 2; ++fml)
#pragma unroll
            for (int fn = 0; fn < 4; ++fn) {
                *(f32x4*)&r2[0 * 8192 + ((fml * 4 + fn) * 64 + lane) * 16] = acc[0 + fml][fn];
                *(f32x4*)&r2[1 * 8192 + ((fml * 4 + fn) * 64 + lane) * 16] = acc[2 + fml][fn];
                *(f32x4*)&r2[2 * 8192 + ((fml * 4 + fn) * 64 + lane) * 16] = acc[6 + fml][fn];
            }
    }
    __syncthreads();
    f32x4 own[2][4];
    {
        const char* rA = red + (size_t)(nq * 2 + 0) * 24576;  // from kq0 (s01)
        const char* rB = red + (size_t)(nq * 2 + 1) * 24576;  // from kq2 (s23)
        if (kq == 0) {
#pragma unroll
            for (int fml = 0; fml < 2; ++fml)
#pragma unroll
                for (int fn = 0; fn < 4; ++fn)
                    own[fml][fn] = acc[fml][fn] +
                        *(const f32x4*)&rB[0 * 8192 + ((fml * 4 + fn) * 64 + lane) * 16];
        } else if (kq == 1) {
#pragma unroll
            for (int fml = 0; fml < 2; ++fml)
#pragma unroll
                for (int fn = 0; fn < 4; ++fn)
                    own[fml][fn] =
                        *(const f32x4*)&rA[0 * 8192 + ((fml * 4 + fn) * 64 + lane) * 16] +
                        *(const f32x4*)&rB[1 * 8192 + ((fml * 4 + fn) * 64 + lane) * 16];
        } else if (kq == 2) {
#pragma unroll
            for (int fml = 0; fml < 2; ++fml)
#pragma unroll
                for (int fn = 0; fn < 4; ++fn)
                    own[fml][fn] = acc[4 + fml][fn] +
                        *(const f32x4*)&rA[1 * 8192 + ((fml * 4 + fn) * 64 + lane) * 16];
        } else {
#pragma unroll
            for (int fml = 0; fml < 2; ++fml)
#pragma unroll
                for (int fn = 0; fn < 4; ++fn)
                    own[fml][fn] =
                        *(const f32x4*)&rA[2 * 8192 + ((fml * 4 + fn) * 64 + lane) * 16] +
                        *(const f32x4*)&rB[2 * 8192 + ((fml * 4 + fn) * 64 + lane) * 16];
        }
    }
    __syncthreads();   // reduction reads done before transpose overwrites

    // ---- epilogue on OWNED rows: z += Whx*x + bh; tanh; transpose ----
    // acc layout (16x16x32): col = lane&15, row = quad*4 + reg [m89-verified]
    // Wave (nq,kq) owns rows fm {2kq, 2kq+1} (32 rows) x cols cn0..cn0+63.
    // Transpose scratch: wave-private 32 rows x 128 B, XOR-swizzled.
    bf16* Lw = (bf16*)&Ls[0][0] + (size_t)w * 2048;
#pragma unroll
    for (int fml = 0; fml < 2; ++fml) {
        int rb = bm0 + (kq * 2 + fml) * 16 + quad * 4;
        float xv[4];
#pragma unroll
        for (int r = 0; r < 4; ++r) xv[r] = x[(size_t)(rb + r) * TT + t];
#pragma unroll
        for (int fn = 0; fn < 4; ++fn) {
            int col = cn0 + fn * 16 + lrow;
            float wx = Whx[col], bb = bh[col];
            int cbyte = (fn * 16 + lrow) * 2;
#pragma unroll
            for (int r = 0; r < 4; ++r) {
                int row_l = fml * 16 + quad * 4 + r;
                float z = own[fml][fn][r] + wx * xv[r] + bb;
                *(bf16*)((char*)Lw + row_l * 128 +
                         (cbyte ^ ((row_l & 7) << 4))) = (bf16)tanhf(z);
            }
        }
    }
    // read own wave's tile in frag-slot order; 16B coalesced global stores.
#pragma unroll
    for (int fml = 0; fml < 2; ++fml) {
#pragma unroll
        for (int kc = 0; kc < 2; ++kc) {
            int row_l = fml * 16 + lrow;
            int cb    = (kc * 64 + quad * 16) ^ ((row_l & 7) << 4);
            bf16x8 v = *(const bf16x8*)((const char*)Lw + row_l * 128 + cb);
            size_t sub = (size_t)((bm0 >> 4) + kq * 2 + fml) * 64 +
                         (cn0 >> 5) + kc;
            *(bf16x8*)(Sw + (sub * 64 + lane) * 8) = v;
        }
    }
}

// ---------------------------------------------------------------------------
// out[b,c] = sum_h Why[h,c] * S[b,h] + bp[c]   (S frag-major)
// ---------------------------------------------------------------------------
__global__ void out_proj(const bf16* __restrict__ S,
                         const float* __restrict__ Why,   // [H, C]
                         const float* __restrict__ bp,    // [C]
                         float* __restrict__ out) {       // [B, C]
    int b = blockIdx.x, tid = threadIdx.x;
    int h0 = tid * 8;                                     // 256*8 = H exactly
    size_t sub  = (size_t)(b >> 4) * 64 + (h0 >> 5);
    size_t slot = (size_t)(b & 15) | (size_t)(((h0 >> 3) & 3) << 4);
    bf16x8 v = *(const bf16x8*)(S + (sub * 64 + slot) * 8);
    float p[NC];
#pragma unroll
    for (int c = 0; c < NC; ++c) p[c] = 0.f;
#pragma unroll
    for (int j = 0; j < 8; ++j) {
        float s = (float)v[j];
        const float* wr = Why + (size_t)(h0 + j) * NC;
#pragma unroll
        for (int c = 0; c < NC; ++c) p[c] += s * wr[c];
    }
    __shared__ float red[256 * NC];
#pragma unroll
    for (int c = 0; c < NC; ++c) red[tid * NC + c] = p[c];
    __syncthreads();
    for (int s = 128; s > 0; s >>= 1) {
        if (tid < s)
#pragma unroll
            for (int c = 0; c < NC; ++c) red[tid * NC + c] += red[(tid + s) * NC + c];
        __syncthreads();
    }
    if (tid < NC) out[(size_t)b * NC + tid] = red[tid] + bp[tid];
}

// ---------------------------------------------------------------------------
extern "C" void kernel_launch(void* const* d_in, const int* in_sizes, int n_in,
                              void* d_out, int out_size, void* d_ws, size_t ws_size,
                              hipStream_t stream) {
    const float* x   = (const float*)d_in[0];   // [B, T]
    const float* Whx = (const float*)d_in[1];   // [H, 1]
    const float* Whh = (const float*)d_in[2];   // [H, H]
    const float* Why = (const float*)d_in[3];   // [H, C]
    const float* bh  = (const float*)d_in[4];   // [H, 1]
    const float* bp  = (const float*)d_in[5];   // [C, 1]
    float* out = (float*)d_out;

    // workspace: Wshuf (8 MB) | S0 (8 MB) | S1 (8 MB)   (all frag-major)
    bf16* Wshuf = (bf16*)d_ws;
    bf16* S0 = (bf16*)((char*)d_ws + (size_t)8 * 1024 * 1024);
    bf16* S1 = (bf16*)((char*)d_ws + (size_t)16 * 1024 * 1024);

    hipLaunchKernelGGL(w_shuffle_kernel, dim3((H * H / 8) / 256), dim3(256),
                       0, stream, Whh, Wshuf);

    // t = 0 writes S1; step t reads (t&1 ? S1 : S0), writes the other.
    hipLaunchKernelGGL(rnn_init, dim3(BB), dim3(256), 0, stream, x, Whx, bh, S1);

    for (int t = 1; t < TT; ++t) {
        const bf16* Srd = (t & 1) ? S1 : S0;
        bf16*       Swr = (t & 1) ? S0 : S1;
        hipLaunchKernelGGL(rnn_step, dim3(256), dim3(512), 0, stream,
                           x, Whx, bh, Wshuf, Srd, Swr, t);
    }

    // t=63 (odd) wrote S0
    hipLaunchKernelGGL(out_proj, dim3(BB), dim3(256), 0, stream, S0, Why, bp, out);
}

// Round 13
// 1532.259 us; speedup vs baseline: 1.1288x; 1.0542x over previous
//
#include <hip/hip_runtime.h>
#include <cstdint>
#include <cstddef>
#include <cmath>

#define H  2048
#define BB 2048   // batch
#define TT 64     // time steps
#define NC 10     // classes

typedef __bf16 bf16;
typedef bf16  bf16x8 __attribute__((ext_vector_type(8)));
typedef float f32x4  __attribute__((ext_vector_type(4)));

// ---------------------------------------------------------------------------
// async global->LDS, 16B per lane. LDS dest is wave-uniform base + lane*16;
// global source is per-lane.
// ---------------------------------------------------------------------------
__device__ __forceinline__ void load_lds16(const void* g, void* l) {
    __builtin_amdgcn_global_load_lds(
        (__attribute__((address_space(1))) void*)(void*)g,
        (__attribute__((address_space(3))) void*)l,
        16, 0, 0);
}

// ---------------------------------------------------------------------------
// FRAG-MAJOR layout (W_hh and S, since R12).
// For a matrix [R rows][H k-cols] (bf16):
//   subtile (r16, k32) = 16 rows x 32 k = 1024 B at id = r16*(H/32) + k32.
//   lane-slot l (16 B) holds M[r16*16 + (l&15)][k32*32 + (l>>4)*8 .. +8]
// = exactly the v_mfma_f32_16x16x32_bf16 A/B fragment, so a wave's frag load
// is ONE coalesced 1 KB segment: base + id*512 + lane*8 (bf16 elems).
// ---------------------------------------------------------------------------
__global__ void w_shuffle_kernel(const float* __restrict__ Whh,
                                 bf16* __restrict__ Wshuf) {
    int tid = blockIdx.x * blockDim.x + threadIdx.x;   // 0 .. H*H/8-1
    int sub = tid >> 6;          // subtile id
    int l   = tid & 63;          // dest lane slot
    int n16 = sub >> 6;          // 0..127
    int k32 = sub & 63;          // 0..63
    int n = n16 * 16 + (l & 15);
    int k = k32 * 32 + (l >> 4) * 8;
    const float* src = Whh + (size_t)n * H + k;
    bf16x8 o;
#pragma unroll
    for (int j = 0; j < 8; ++j) o[j] = (bf16)src[j];
    *(bf16x8*)(Wshuf + (size_t)tid * 8) = o;
}

// ---------------------------------------------------------------------------
// t = 0: S[b,i] = tanh(Whx[i]*x[b,0] + bh[i]), written FRAG-MAJOR.
// ---------------------------------------------------------------------------
__global__ void rnn_init(const float* __restrict__ x,     // [B, T]
                         const float* __restrict__ Whx,   // [H]
                         const float* __restrict__ bh,    // [H]
                         bf16* __restrict__ S) {          // frag-major
    int b  = blockIdx.x;
    int i0 = threadIdx.x * 8;
    float xv = x[(size_t)b * TT];
    bf16x8 o;
#pragma unroll
    for (int j = 0; j < 8; ++j)
        o[j] = (bf16)tanhf(Whx[i0 + j] * xv + bh[i0 + j]);
    size_t sub  = (size_t)(b >> 4) * 64 + (i0 >> 5);
    size_t slot = (size_t)(b & 15) | (size_t)(((i0 >> 3) & 3) << 4);
    *(bf16x8*)(S + (sub * 64 + slot) * 8) = o;
}

// ---------------------------------------------------------------------------
// One RNN time step, Round-23 = R19 (1412us best) + barrier-every-2-phases:
//   Sw[b,i] = tanh( sum_k Sr[b,k]*W[i,k] + Whx[i]*x[b,t] + bh[i] )
//
// R22 post-mortem: parity phases refuted (1615). R19's loop runs at ~85-88%
// of the LDS instruction-issue floor; the extractable remainder is the
// per-phase barrier join (~150-250cy x 32). R23 halves the barrier count:
//
//   - Barriers only at EVEN phases. At even q, issue BOTH stage(q+3)
//     -> slot (q-1)&3 (read in phase q-2, two barriers back) and
//     stage(q+4) -> slot q&3 (its DSREAD ran in phase q-1, complete before
//     this barrier). Odd phases keep only a per-wave counted wait.
//   - Wait counts (4 ops/stage): even top: outstanding {q+1,q+2} -> wait
//     vmcnt(4). Odd top: outstanding {q+1,q+2,q+3} -> wait vmcnt(8).
//     Tail 4/4/0. NEVER 0 in steady state.
//   - Cross-phase read-ahead unchanged: DSREAD(p+1) during phase p into
//     ping-pong banks (static names, rule #20).
//   - Epilogue x-gathers hoisted before the reduction (latency hidden
//     under LDS reduction traffic).
//   - Split-K-2 geometry, pair reduction, transpose epilogue identical to
//     R19 -> absmax unchanged (2.441e-4). __launch_bounds__(512,2) pinned
//     (R20 lesson: large live state NEEDS the explicit occupancy target).
// ---------------------------------------------------------------------------
#define PH_WAIT(NSTR) asm volatile("s_waitcnt vmcnt(" NSTR ")" ::: "memory")
#define SBAR0()       __builtin_amdgcn_sched_barrier(0)

__launch_bounds__(512, 2)
__global__ void rnn_step(const float* __restrict__ x,     // [B, T]
                         const float* __restrict__ Whx,   // [H]
                         const float* __restrict__ bh,    // [H]
                         const bf16*  __restrict__ Wshuf, // frag-major W_hh
                         const bf16*  __restrict__ Sr,    // frag-major S read
                         bf16* __restrict__ Sw,           // frag-major S write
                         int t) {
    // ring slot = 32 segs x 1 KB:
    //   segs  0..7  = A m16 0..7, chunk-lo   segs  8..15 = B n16 0..7, lo
    //   segs 16..23 = A m16 0..7, chunk-hi   segs 24..31 = B n16 0..7, hi
    __shared__ __align__(16) char Ls[4][32768];   // 128 KB -> 1 block/CU

    const int tid  = threadIdx.x;
    const int w    = tid >> 6;          // wave 0..7
    const int lane = tid & 63;
    const int lrow = lane & 15;
    const int quad = lane >> 4;

    // XCD-owns-n mapping: XCD x covers n-cols [x*256, x*256+256).
    const int xcd = blockIdx.x & 7;
    const int loc = blockIdx.x >> 3;               // 0..31
    const int bm0 = (loc >> 1) * 128;              // batch-row tile origin
    const int bn0 = xcd * 256 + (loc & 1) * 128;   // hidden-col tile origin

    const int kh   = w >> 2;                       // K-half (0: k<1024)
    const int s    = w & 3;                        // quadrant id
    const int qm   = s & 1;                        // m-quadrant (64 rows)
    const int qn   = s >> 1;                       // n-quadrant (64 cols)
    const int cn0  = bn0 + qn * 64;                // wave's first col
    const int kh16 = kh * 16;                      // seg offset of own half

    // staging sources (per wave): wave w owns A m16 subtile (bm0>>4)+w and
    // B n16 subtile (bn0>>4)+w, BOTH k-halves. 1 KB per k32, +lane*16B.
    const char* srcA = (const char*)Sr +
        ((size_t)((bm0 >> 4) + w) * 64) * 1024 + (size_t)lane * 16;
    const char* srcB = (const char*)Wshuf +
        ((size_t)((bn0 >> 4) + w) * 64) * 1024 + (size_t)lane * 16;

    f32x4 acc[4][4];
#pragma unroll
    for (int i = 0; i < 4; ++i)
#pragma unroll
        for (int j = 0; j < 4; ++j) acc[i][j] = (f32x4){0.f, 0.f, 0.f, 0.f};

    // fragment ping-pong banks (static names; rule #20)
    bf16x8 Ae[4], Be[4], Ao[4], Bo[4];

    // ---- issue section for phase pp into ring slot RI (4 VMEM ops) ----
#define ISSUE(RI, pp)                                                        \
    {                                                                        \
        load_lds16(srcA + (size_t)(pp) * 1024,        &Ls[RI][w * 1024]);    \
        load_lds16(srcB + (size_t)(pp) * 1024,        &Ls[RI][(8 + w) * 1024]); \
        load_lds16(srcA + (size_t)(32 + (pp)) * 1024, &Ls[RI][(16 + w) * 1024]); \
        load_lds16(srcB + (size_t)(32 + (pp)) * 1024, &Ls[RI][(24 + w) * 1024]); \
    }

    // ---- read fragments of ring slot RI into bank (Ax, Bx) ----
#define DSREAD(Ax, Bx, RI)                                                   \
    {                                                                        \
        _Pragma("unroll")                                                    \
        for (int fm = 0; fm < 4; ++fm)                                       \
            Ax[fm] = *(const bf16x8*)&Ls[RI]                                 \
                [(kh16 + qm * 4 + fm) * 1024 + lane * 16];                   \
        _Pragma("unroll")                                                    \
        for (int fn = 0; fn < 4; ++fn)                                       \
            Bx[fn] = *(const bf16x8*)&Ls[RI]                                 \
                [(kh16 + 8 + qn * 4 + fn) * 1024 + lane * 16];               \
    }

    // ---- 16 MFMAs on bank (Ax, Bx) ----
#define MFMAS(Ax, Bx)                                                        \
    {                                                                        \
        __builtin_amdgcn_s_setprio(1);                                       \
        _Pragma("unroll")                                                    \
        for (int fm = 0; fm < 4; ++fm)                                       \
            _Pragma("unroll")                                                \
            for (int fn = 0; fn < 4; ++fn)                                   \
                acc[fm][fn] = __builtin_amdgcn_mfma_f32_16x16x32_bf16(       \
                    Ax[fm], Bx[fn], acc[fm][fn], 0, 0, 0);                   \
        __builtin_amdgcn_s_setprio(0);                                       \
    }

    // even phase p: wait, barrier, paired issue (p+3, p+4), read-ahead, MFMA
#define PHASE_E(RNext, RIs1, RIs2, p, W, NISS, DOREAD, AN, BN, AC, BC)       \
    {                                                                        \
        SBAR0(); PH_WAIT(W); SBAR0();                                        \
        __builtin_amdgcn_s_barrier(); SBAR0();                               \
        if (NISS >= 1) ISSUE(RIs1, (p) + 3);                                 \
        if (NISS >= 2) ISSUE(RIs2, (p) + 4);                                 \
        if (DOREAD) DSREAD(AN, BN, RNext);                                   \
        MFMAS(AC, BC);                                                       \
    }
    // odd phase p: counted wait only (no join), read-ahead, MFMA
#define PHASE_O(RNext, p, W, DOREAD, AN, BN, AC, BC)                         \
    {                                                                        \
        SBAR0(); PH_WAIT(W); SBAR0();                                        \
        if (DOREAD) DSREAD(AN, BN, RNext);                                   \
        MFMAS(AC, BC);                                                       \
    }

    // prologue: issue phases 0,1,2 (12 ops); wait stage(0) (8 newer);
    // barrier; pre-read slot 0.
    ISSUE(0, 0); SBAR0();
    ISSUE(1, 1); SBAR0();
    ISSUE(2, 2); SBAR0();
    PH_WAIT("8"); SBAR0();
    __builtin_amdgcn_s_barrier(); SBAR0();
    DSREAD(Ae, Be, 0);

    // main loop: phases 0..27 (7 macro-iters x 4)
    // even p (p%4==0): issue slots 3,0 ; even p+2: issue slots 1,2
#pragma unroll 1
    for (int q = 0; q < 7; ++q) {
        int p = 4 * q;
        PHASE_E(1, 3, 0, p + 0, "4", 2, 1, Ao, Bo, Ae, Be);
        PHASE_O(2,       p + 1, "8",    1, Ae, Be, Ao, Bo);
        PHASE_E(3, 1, 2, p + 2, "4", 2, 1, Ao, Bo, Ae, Be);
        PHASE_O(0,       p + 3, "8",    1, Ae, Be, Ao, Bo);
    }
    // peeled tail: phases 28..31
    PHASE_E(1, 3, 0, 28, "4", 1, 1, Ao, Bo, Ae, Be);   // issues stage 31 only
    PHASE_O(2,       29, "4",    1, Ae, Be, Ao, Bo);
    PHASE_E(3, 1, 2, 30, "0", 0, 1, Ao, Bo, Ae, Be);
    PHASE_O(0,       31, "0",    0, Ae, Be, Ao, Bo);   // compute-only

#undef PHASE_E
#undef PHASE_O
#undef MFMAS
#undef DSREAD
#undef ISSUE

    // ---- epilogue x-gathers hoisted: hide latency under the reduction ----
    float xva[2][4];
#pragma unroll
    for (int fml = 0; fml < 2; ++fml) {
        int rb = bm0 + qm * 64 + (kh * 2 + fml) * 16 + quad * 4;
#pragma unroll
        for (int r = 0; r < 4; ++r)
            xva[fml][r] = x[(size_t)(rb + r) * TT + t];
    }

    // ---- split-K pair reduction (slots 0-1; all stages drained) ----
    // ALL acc indices below are compile-time constants (rule #20).
    // kh=0 donates fm{2,3}; kh=1 donates fm{0,1}; own = kept + partner.
    char* red = &Ls[0][0];
    const int pairbase = s * 16384;
    if (kh == 0) {
#pragma unroll
        for (int fml = 0; fml < 2; ++fml)
#pragma unroll
            for (int fn = 0; fn < 4; ++fn)
                *(f32x4*)&red[pairbase + (fml * 4 + fn) * 1024 + lane * 16] =
                    acc[2 + fml][fn];
    } else {
#pragma unroll
        for (int fml = 0; fml < 2; ++fml)
#pragma unroll
            for (int fn = 0; fn < 4; ++fn)
                *(f32x4*)&red[pairbase + 8192 + (fml * 4 + fn) * 1024 +
                              lane * 16] = acc[fml][fn];
    }
    __syncthreads();
    f32x4 own[2][4];
    if (kh == 0) {
#pragma unroll
        for (int fml = 0; fml < 2; ++fml)
#pragma unroll
            for (int fn = 0; fn < 4; ++fn)
                own[fml][fn] = acc[fml][fn] + *(const f32x4*)&red[pairbase +
                    8192 + (fml * 4 + fn) * 1024 + lane * 16];
    } else {
#pragma unroll
        for (int fml = 0; fml < 2; ++fml)
#pragma unroll
            for (int fn = 0; fn < 4; ++fn)
                own[fml][fn] = acc[2 + fml][fn] + *(const f32x4*)&red[pairbase +
                    (fml * 4 + fn) * 1024 + lane * 16];
    }
    __syncthreads();   // reduction reads done before transpose overwrites

    // ---- epilogue on OWNED rows: z += Whx*x + bh; tanh; transpose ----
    // acc layout (16x16x32): col = lane&15, row = quad*4 + reg [m89-verified]
    // Owned global fm = kh*2 + fml (address math only; own[] is static-idx).
    // Transpose scratch: wave-private 32 rows x 128 B at flat + w*2048.
    bf16* Lw = (bf16*)&Ls[0][0] + (size_t)w * 2048;
#pragma unroll
    for (int fml = 0; fml < 2; ++fml) {
#pragma unroll
        for (int fn = 0; fn < 4; ++fn) {
            int col = cn0 + fn * 16 + lrow;
            float wx = Whx[col], bb = bh[col];
            int cbyte = (fn * 16 + lrow) * 2;
#pragma unroll
            for (int r = 0; r < 4; ++r) {
                int row_l = fml * 16 + quad * 4 + r;
                float z = own[fml][fn][r] + wx * xva[fml][r] + bb;
                *(bf16*)((char*)Lw + row_l * 128 +
                         (cbyte ^ ((row_l & 7) << 4))) = (bf16)tanhf(z);
            }
        }
    }
    // read own wave's tile in frag-slot order; 16B coalesced global stores.
#pragma unroll
    for (int fml = 0; fml < 2; ++fml) {
#pragma unroll
        for (int kc = 0; kc < 2; ++kc) {
            int row_l = fml * 16 + lrow;
            int cb    = (kc * 64 + quad * 16) ^ ((row_l & 7) << 4);
            bf16x8 v = *(const bf16x8*)((const char*)Lw + row_l * 128 + cb);
            size_t sub = (size_t)((bm0 >> 4) + qm * 4 + kh * 2 + fml) * 64 +
                         (cn0 >> 5) + kc;
            *(bf16x8*)(Sw + (sub * 64 + lane) * 8) = v;
        }
    }
}

// ---------------------------------------------------------------------------
// out[b,c] = sum_h Why[h,c] * S[b,h] + bp[c]   (S frag-major)
// ---------------------------------------------------------------------------
__global__ void out_proj(const bf16* __restrict__ S,
                         const float* __restrict__ Why,   // [H, C]
                         const float* __restrict__ bp,    // [C]
                         float* __restrict__ out) {       // [B, C]
    int b = blockIdx.x, tid = threadIdx.x;
    int h0 = tid * 8;                                     // 256*8 = H exactly
    size_t sub  = (size_t)(b >> 4) * 64 + (h0 >> 5);
    size_t slot = (size_t)(b & 15) | (size_t)(((h0 >> 3) & 3) << 4);
    bf16x8 v = *(const bf16x8*)(S + (sub * 64 + slot) * 8);
    float p[NC];
#pragma unroll
    for (int c = 0; c < NC; ++c) p[c] = 0.f;
#pragma unroll
    for (int j = 0; j < 8; ++j) {
        float s = (float)v[j];
        const float* wr = Why + (size_t)(h0 + j) * NC;
#pragma unroll
        for (int c = 0; c < NC; ++c) p[c] += s * wr[c];
    }
    __shared__ float red[256 * NC];
#pragma unroll
    for (int c = 0; c < NC; ++c) red[tid * NC + c] = p[c];
    __syncthreads();
    for (int s = 128; s > 0; s >>= 1) {
        if (tid < s)
#pragma unroll
            for (int c = 0; c < NC; ++c) red[tid * NC + c] += red[(tid + s) * NC + c];
        __syncthreads();
    }
    if (tid < NC) out[(size_t)b * NC + tid] = red[tid] + bp[tid];
}

// ---------------------------------------------------------------------------
extern "C" void kernel_launch(void* const* d_in, const int* in_sizes, int n_in,
                              void* d_out, int out_size, void* d_ws, size_t ws_size,
                              hipStream_t stream) {
    const float* x   = (const float*)d_in[0];   // [B, T]
    const float* Whx = (const float*)d_in[1];   // [H, 1]
    const float* Whh = (const float*)d_in[2];   // [H, H]
    const float* Why = (const float*)d_in[3];   // [H, C]
    const float* bh  = (const float*)d_in[4];   // [H, 1]
    const float* bp  = (const float*)d_in[5];   // [C, 1]
    float* out = (float*)d_out;

    // workspace: Wshuf (8 MB) | S0 (8 MB) | S1 (8 MB)   (all frag-major)
    bf16* Wshuf = (bf16*)d_ws;
    bf16* S0 = (bf16*)((char*)d_ws + (size_t)8 * 1024 * 1024);
    bf16* S1 = (bf16*)((char*)d_ws + (size_t)16 * 1024 * 1024);

    hipLaunchKernelGGL(w_shuffle_kernel, dim3((H * H / 8) / 256), dim3(256),
                       0, stream, Whh, Wshuf);

    // t = 0 writes S1; step t reads (t&1 ? S1 : S0), writes the other.
    hipLaunchKernelGGL(rnn_init, dim3(BB), dim3(256), 0, stream, x, Whx, bh, S1);

    for (int t = 1; t < TT; ++t) {
        const bf16* Srd = (t & 1) ? S1 : S0;
        bf16*       Swr = (t & 1) ? S0 : S1;
        hipLaunchKernelGGL(rnn_step, dim3(256), dim3(512), 0, stream,
                           x, Whx, bh, Wshuf, Srd, Swr, t);
    }

    // t=63 (odd) wrote S0
    hipLaunchKernelGGL(out_proj, dim3(BB), dim3(256), 0, stream, S0, Why, bp, out);
}

// Round 14
// 1525.200 us; speedup vs baseline: 1.1340x; 1.0046x over previous
//
#include <hip/hip_runtime.h>
#include <cstdint>
#include <cstddef>
#include <cmath>

#define H  2048
#define BB 2048   // batch
#define TT 64     // time steps
#define NC 10     // classes

typedef __bf16 bf16;
typedef bf16  bf16x8 __attribute__((ext_vector_type(8)));
typedef float f32x4  __attribute__((ext_vector_type(4)));

// ---------------------------------------------------------------------------
// async global->LDS, 16B per lane. LDS dest is wave-uniform base + lane*16;
// global source is per-lane.
// ---------------------------------------------------------------------------
__device__ __forceinline__ void load_lds16(const void* g, void* l) {
    __builtin_amdgcn_global_load_lds(
        (__attribute__((address_space(1))) void*)(void*)g,
        (__attribute__((address_space(3))) void*)l,
        16, 0, 0);
}

// ---------------------------------------------------------------------------
// FRAG-MAJOR layout (W_hh and S, since R12).
// For a matrix [R rows][H k-cols] (bf16):
//   subtile (r16, k32) = 16 rows x 32 k = 1024 B at id = r16*(H/32) + k32.
//   lane-slot l (16 B) holds M[r16*16 + (l&15)][k32*32 + (l>>4)*8 .. +8]
// = exactly the v_mfma_f32_16x16x32_bf16 A/B fragment, so a wave's frag load
// is ONE coalesced 1 KB segment: base + id*512 + lane*8 (bf16 elems).
// ---------------------------------------------------------------------------
__global__ void w_shuffle_kernel(const float* __restrict__ Whh,
                                 bf16* __restrict__ Wshuf) {
    int tid = blockIdx.x * blockDim.x + threadIdx.x;   // 0 .. H*H/8-1
    int sub = tid >> 6;          // subtile id
    int l   = tid & 63;          // dest lane slot
    int n16 = sub >> 6;          // 0..127
    int k32 = sub & 63;          // 0..63
    int n = n16 * 16 + (l & 15);
    int k = k32 * 32 + (l >> 4) * 8;
    const float* src = Whh + (size_t)n * H + k;
    bf16x8 o;
#pragma unroll
    for (int j = 0; j < 8; ++j) o[j] = (bf16)src[j];
    *(bf16x8*)(Wshuf + (size_t)tid * 8) = o;
}

// ---------------------------------------------------------------------------
// t = 0: S[b,i] = tanh(Whx[i]*x[b,0] + bh[i]), written FRAG-MAJOR.
// ---------------------------------------------------------------------------
__global__ void rnn_init(const float* __restrict__ x,     // [B, T]
                         const float* __restrict__ Whx,   // [H]
                         const float* __restrict__ bh,    // [H]
                         bf16* __restrict__ S) {          // frag-major
    int b  = blockIdx.x;
    int i0 = threadIdx.x * 8;
    float xv = x[(size_t)b * TT];
    bf16x8 o;
#pragma unroll
    for (int j = 0; j < 8; ++j)
        o[j] = (bf16)tanhf(Whx[i0 + j] * xv + bh[i0 + j]);
    size_t sub  = (size_t)(b >> 4) * 64 + (i0 >> 5);
    size_t slot = (size_t)(b & 15) | (size_t)(((i0 >> 3) & 3) << 4);
    *(bf16x8*)(S + (sub * 64 + slot) * 8) = o;
}

// ---------------------------------------------------------------------------
// One RNN time step, Round-24 = EXACT REVERT to Round-19 (1412 us, session
// best):
//   Sw[b,i] = tanh( sum_k Sr[b,k]*W[i,k] + Whx[i]*x[b,t] + bh[i] )
//
// Final evidence summary: every deviation from this schedule measured worse
//   - R18: lower LDS amplification (96 KB/phase) ......... neutral (1526)
//   - R21: B over VMEM (L2-resident W) ................... worse  (1719)
//   - R22: 128x64 tiles, parity phases (0.375 rd/MFMA) ... worse  (1615)
//   - R23: barrier every 2 phases ........................ worse  (1532)
// R19 runs at ~85-88% of the LDS instruction-issue floor for its dataflow
// (64 ds_read_b128 + 32 KB stage-writes per phase vs 620cy MFMA), with the
// ds_read latency hidden by cross-phase read-ahead.
//
// Protocol per phase p: s_waitcnt vmcnt(4) [stages p AND p+1 resident;
// issue depth 3], s_barrier (raw, no drain), ISSUE(p+3), ds_read slot(p+1)
// -> next bank (ping-pong Ae/Be <-> Ao/Bo, static names), MFMA on current.
// Slot safety: write slot (p+3)&3 = (p-1)&3, last read phase p-2, two
// barriers ago. Tail peels wait 4/4/0/0.
// Split-K-2: 8 waves = (kh, quadrant); pair reduction via LDS slots 0/1;
// 8-wave-parallel tanh epilogue + frag-major transpose store.
// __launch_bounds__(512, 2) pinned (R20 lesson).
// ---------------------------------------------------------------------------
#define PH_WAIT(NSTR) asm volatile("s_waitcnt vmcnt(" NSTR ")" ::: "memory")
#define SBAR0()       __builtin_amdgcn_sched_barrier(0)

__launch_bounds__(512, 2)
__global__ void rnn_step(const float* __restrict__ x,     // [B, T]
                         const float* __restrict__ Whx,   // [H]
                         const float* __restrict__ bh,    // [H]
                         const bf16*  __restrict__ Wshuf, // frag-major W_hh
                         const bf16*  __restrict__ Sr,    // frag-major S read
                         bf16* __restrict__ Sw,           // frag-major S write
                         int t) {
    // ring slot = 32 segs x 1 KB:
    //   segs  0..7  = A m16 0..7, chunk-lo   segs  8..15 = B n16 0..7, lo
    //   segs 16..23 = A m16 0..7, chunk-hi   segs 24..31 = B n16 0..7, hi
    __shared__ __align__(16) char Ls[4][32768];   // 128 KB -> 1 block/CU

    const int tid  = threadIdx.x;
    const int w    = tid >> 6;          // wave 0..7
    const int lane = tid & 63;
    const int lrow = lane & 15;
    const int quad = lane >> 4;

    // XCD-owns-n mapping: XCD x covers n-cols [x*256, x*256+256).
    const int xcd = blockIdx.x & 7;
    const int loc = blockIdx.x >> 3;               // 0..31
    const int bm0 = (loc >> 1) * 128;              // batch-row tile origin
    const int bn0 = xcd * 256 + (loc & 1) * 128;   // hidden-col tile origin

    const int kh   = w >> 2;                       // K-half (0: k<1024)
    const int s    = w & 3;                        // quadrant id
    const int qm   = s & 1;                        // m-quadrant (64 rows)
    const int qn   = s >> 1;                       // n-quadrant (64 cols)
    const int cn0  = bn0 + qn * 64;                // wave's first col
    const int kh16 = kh * 16;                      // seg offset of own half

    // staging sources (per wave): wave w owns A m16 subtile (bm0>>4)+w and
    // B n16 subtile (bn0>>4)+w, BOTH k-halves. 1 KB per k32, +lane*16B.
    const char* srcA = (const char*)Sr +
        ((size_t)((bm0 >> 4) + w) * 64) * 1024 + (size_t)lane * 16;
    const char* srcB = (const char*)Wshuf +
        ((size_t)((bn0 >> 4) + w) * 64) * 1024 + (size_t)lane * 16;

    f32x4 acc[4][4];
#pragma unroll
    for (int i = 0; i < 4; ++i)
#pragma unroll
        for (int j = 0; j < 4; ++j) acc[i][j] = (f32x4){0.f, 0.f, 0.f, 0.f};

    // fragment ping-pong banks (static names; rule #20)
    bf16x8 Ae[4], Be[4], Ao[4], Bo[4];

    // ---- issue section for phase pp into ring slot RI (4 VMEM ops) ----
#define ISSUE(RI, pp)                                                        \
    {                                                                        \
        load_lds16(srcA + (size_t)(pp) * 1024,        &Ls[RI][w * 1024]);    \
        load_lds16(srcB + (size_t)(pp) * 1024,        &Ls[RI][(8 + w) * 1024]); \
        load_lds16(srcA + (size_t)(32 + (pp)) * 1024, &Ls[RI][(16 + w) * 1024]); \
        load_lds16(srcB + (size_t)(32 + (pp)) * 1024, &Ls[RI][(24 + w) * 1024]); \
    }

    // ---- read fragments of ring slot RI into bank (Ax, Bx) ----
#define DSREAD(Ax, Bx, RI)                                                   \
    {                                                                        \
        _Pragma("unroll")                                                    \
        for (int fm = 0; fm < 4; ++fm)                                       \
            Ax[fm] = *(const bf16x8*)&Ls[RI]                                 \
                [(kh16 + qm * 4 + fm) * 1024 + lane * 16];                   \
        _Pragma("unroll")                                                    \
        for (int fn = 0; fn < 4; ++fn)                                       \
            Bx[fn] = *(const bf16x8*)&Ls[RI]                                 \
                [(kh16 + 8 + qn * 4 + fn) * 1024 + lane * 16];               \
    }

    // ---- 16 MFMAs on bank (Ax, Bx) ----
#define MFMAS(Ax, Bx)                                                        \
    {                                                                        \
        __builtin_amdgcn_s_setprio(1);                                       \
        _Pragma("unroll")                                                    \
        for (int fm = 0; fm < 4; ++fm)                                       \
            _Pragma("unroll")                                                \
            for (int fn = 0; fn < 4; ++fn)                                   \
                acc[fm][fn] = __builtin_amdgcn_mfma_f32_16x16x32_bf16(       \
                    Ax[fm], Bx[fn], acc[fm][fn], 0, 0, 0);                   \
        __builtin_amdgcn_s_setprio(0);                                       \
    }

    // phase p: wait W, barrier, issue p+3 (DOISS), read slot RNext into
    // next bank (DOREAD), MFMA on current bank.
#define PHASE(RNext, RIss, p, W, DOISS, DOREAD, AN, BN, AC, BC)              \
    {                                                                        \
        PH_WAIT(W);                                                          \
        SBAR0();                                                             \
        __builtin_amdgcn_s_barrier();                                        \
        SBAR0();                                                             \
        if (DOISS) ISSUE(RIss, (p) + 3);                                     \
        if (DOREAD) DSREAD(AN, BN, RNext);                                   \
        MFMAS(AC, BC);                                                       \
    }

    // prologue: issue phases 0,1,2; wait phase-0 landed; pre-read slot 0.
    ISSUE(0, 0); SBAR0();
    ISSUE(1, 1); SBAR0();
    ISSUE(2, 2); SBAR0();
    PH_WAIT("8");
    SBAR0();
    __builtin_amdgcn_s_barrier();
    SBAR0();
    DSREAD(Ae, Be, 0);

    // main loop: phases 0..27 (7 macro-iters x 4), steady wait = 4
#pragma unroll 1
    for (int q = 0; q < 7; ++q) {
        int p = 4 * q;
        PHASE(1, 3, p + 0, "4", 1, 1, Ao, Bo, Ae, Be);
        PHASE(2, 0, p + 1, "4", 1, 1, Ae, Be, Ao, Bo);
        PHASE(3, 1, p + 2, "4", 1, 1, Ao, Bo, Ae, Be);
        PHASE(0, 2, p + 3, "4", 1, 1, Ae, Be, Ao, Bo);
    }
    // peeled tail: phases 28..31
    PHASE(1, 3, 28, "4", 1, 1, Ao, Bo, Ae, Be);   // issues phase 31 -> slot3
    PHASE(2, 0, 29, "4", 0, 1, Ae, Be, Ao, Bo);
    PHASE(3, 1, 30, "0", 0, 1, Ao, Bo, Ae, Be);
    PHASE(0, 2, 31, "0", 0, 0, Ae, Be, Ao, Bo);   // compute-only

#undef PHASE
#undef MFMAS
#undef DSREAD
#undef ISSUE

    // ---- split-K pair reduction (slots 0-1; all gload_lds drained) ----
    // ALL acc indices below are compile-time constants (rule #20).
    // kh=0 donates fm{2,3}; kh=1 donates fm{0,1}; own = kept + partner.
    char* red = &Ls[0][0];
    const int pairbase = s * 16384;
    if (kh == 0) {
#pragma unroll
        for (int fml = 0; fml < 2; ++fml)
#pragma unroll
            for (int fn = 0; fn < 4; ++fn)
                *(f32x4*)&red[pairbase + (fml * 4 + fn) * 1024 + lane * 16] =
                    acc[2 + fml][fn];
    } else {
#pragma unroll
        for (int fml = 0; fml < 2; ++fml)
#pragma unroll
            for (int fn = 0; fn < 4; ++fn)
                *(f32x4*)&red[pairbase + 8192 + (fml * 4 + fn) * 1024 +
                              lane * 16] = acc[fml][fn];
    }
    __syncthreads();
    f32x4 own[2][4];
    if (kh == 0) {
#pragma unroll
        for (int fml = 0; fml < 2; ++fml)
#pragma unroll
            for (int fn = 0; fn < 4; ++fn)
                own[fml][fn] = acc[fml][fn] + *(const f32x4*)&red[pairbase +
                    8192 + (fml * 4 + fn) * 1024 + lane * 16];
    } else {
#pragma unroll
        for (int fml = 0; fml < 2; ++fml)
#pragma unroll
            for (int fn = 0; fn < 4; ++fn)
                own[fml][fn] = acc[2 + fml][fn] + *(const f32x4*)&red[pairbase +
                    (fml * 4 + fn) * 1024 + lane * 16];
    }

    // ---- epilogue on OWNED rows: z += Whx*x + bh; tanh; transpose ----
    // acc layout (16x16x32): col = lane&15, row = quad*4 + reg [m89-verified]
    // Owned global fm = kh*2 + fml (address math only; own[] is static-idx).
    // Transpose scratch: slot 2, wave-private 32 rows x 128 B, XOR-swizzled.
    bf16* Lw = (bf16*)&Ls[2][0] + (size_t)w * 2048;
#pragma unroll
    for (int fml = 0; fml < 2; ++fml) {
        int rb = bm0 + qm * 64 + (kh * 2 + fml) * 16 + quad * 4;
        float xv[4];
#pragma unroll
        for (int r = 0; r < 4; ++r) xv[r] = x[(size_t)(rb + r) * TT + t];
#pragma unroll
        for (int fn = 0; fn < 4; ++fn) {
            int col = cn0 + fn * 16 + lrow;
            float wx = Whx[col], bb = bh[col];
            int cbyte = (fn * 16 + lrow) * 2;
#pragma unroll
            for (int r = 0; r < 4; ++r) {
                int row_l = fml * 16 + quad * 4 + r;
                float z = own[fml][fn][r] + wx * xv[r] + bb;
                *(bf16*)((char*)Lw + row_l * 128 +
                         (cbyte ^ ((row_l & 7) << 4))) = (bf16)tanhf(z);
            }
        }
    }
    // read own wave's tile in frag-slot order; 16B coalesced global stores.
#pragma unroll
    for (int fml = 0; fml < 2; ++fml) {
#pragma unroll
        for (int kc = 0; kc < 2; ++kc) {
            int row_l = fml * 16 + lrow;
            int cb    = (kc * 64 + quad * 16) ^ ((row_l & 7) << 4);
            bf16x8 v = *(const bf16x8*)((const char*)Lw + row_l * 128 + cb);
            size_t sub = (size_t)((bm0 >> 4) + qm * 4 + kh * 2 + fml) * 64 +
                         (cn0 >> 5) + kc;
            *(bf16x8*)(Sw + (sub * 64 + lane) * 8) = v;
        }
    }
}

// ---------------------------------------------------------------------------
// out[b,c] = sum_h Why[h,c] * S[b,h] + bp[c]   (S frag-major)
// ---------------------------------------------------------------------------
__global__ void out_proj(const bf16* __restrict__ S,
                         const float* __restrict__ Why,   // [H, C]
                         const float* __restrict__ bp,    // [C]
                         float* __restrict__ out) {       // [B, C]
    int b = blockIdx.x, tid = threadIdx.x;
    int h0 = tid * 8;                                     // 256*8 = H exactly
    size_t sub  = (size_t)(b >> 4) * 64 + (h0 >> 5);
    size_t slot = (size_t)(b & 15) | (size_t)(((h0 >> 3) & 3) << 4);
    bf16x8 v = *(const bf16x8*)(S + (sub * 64 + slot) * 8);
    float p[NC];
#pragma unroll
    for (int c = 0; c < NC; ++c) p[c] = 0.f;
#pragma unroll
    for (int j = 0; j < 8; ++j) {
        float s = (float)v[j];
        const float* wr = Why + (size_t)(h0 + j) * NC;
#pragma unroll
        for (int c = 0; c < NC; ++c) p[c] += s * wr[c];
    }
    __shared__ float red[256 * NC];
#pragma unroll
    for (int c = 0; c < NC; ++c) red[tid * NC + c] = p[c];
    __syncthreads();
    for (int s = 128; s > 0; s >>= 1) {
        if (tid < s)
#pragma unroll
            for (int c = 0; c < NC; ++c) red[tid * NC + c] += red[(tid + s) * NC + c];
        __syncthreads();
    }
    if (tid < NC) out[(size_t)b * NC + tid] = red[tid] + bp[tid];
}

// ---------------------------------------------------------------------------
extern "C" void kernel_launch(void* const* d_in, const int* in_sizes, int n_in,
                              void* d_out, int out_size, void* d_ws, size_t ws_size,
                              hipStream_t stream) {
    const float* x   = (const float*)d_in[0];   // [B, T]
    const float* Whx = (const float*)d_in[1];   // [H, 1]
    const float* Whh = (const float*)d_in[2];   // [H, H]
    const float* Why = (const float*)d_in[3];   // [H, C]
    const float* bh  = (const float*)d_in[4];   // [H, 1]
    const float* bp  = (const float*)d_in[5];   // [C, 1]
    float* out = (float*)d_out;

    // workspace: Wshuf (8 MB) | S0 (8 MB) | S1 (8 MB)   (all frag-major)
    bf16* Wshuf = (bf16*)d_ws;
    bf16* S0 = (bf16*)((char*)d_ws + (size_t)8 * 1024 * 1024);
    bf16* S1 = (bf16*)((char*)d_ws + (size_t)16 * 1024 * 1024);

    hipLaunchKernelGGL(w_shuffle_kernel, dim3((H * H / 8) / 256), dim3(256),
                       0, stream, Whh, Wshuf);

    // t = 0 writes S1; step t reads (t&1 ? S1 : S0), writes the other.
    hipLaunchKernelGGL(rnn_init, dim3(BB), dim3(256), 0, stream, x, Whx, bh, S1);

    for (int t = 1; t < TT; ++t) {
        const bf16* Srd = (t & 1) ? S1 : S0;
        bf16*       Swr = (t & 1) ? S0 : S1;
        hipLaunchKernelGGL(rnn_step, dim3(256), dim3(512), 0, stream,
                           x, Whx, bh, Wshuf, Srd, Swr, t);
    }

    // t=63 (odd) wrote S0
    hipLaunchKernelGGL(out_proj, dim3(BB), dim3(256), 0, stream, S0, Why, bp, out);
}